// Round 4
// baseline (205.733 us; speedup 1.0000x reference)
//
#include <hip/hip_runtime.h>

#define L_IN   4000
#define CIN    512
#define KSZ    16
#define LOUT   31992   // 8 * 3999
#define NQ     3999    // valid q: 0..3998
#define QPB    128     // q positions per block (2 per thread)
#define RST    1088    // reduction region stride: 64 lanes * 17 floats

// OCCUPANCY CONFIG: grid (32 q-tiles, 16 b, 2 ci-halves) = 1024 blocks of
// 512 threads (8 waves) = exactly 4 blocks/CU co-resident -> 32 waves/CU
// (100% hw occupancy), vs 16 waves/CU in every prior round. Per-thread q
// drops 4->2 (acc 32->16 VGPR) so the kernel fits the 64-VGPR budget that
// 8 waves/SIMD requires (__launch_bounds__(512, 8)).
// Wave w owns ci rows [cih*256 + w*32, +32); thread owns 2 contiguous q
// (qb = q0 + 2*lane) -> per (wave,ci) the x-load is a 512 B float2 burst
// + halo dword. d=2 software pipeline (R1-proven codegen). Weights staged
// to LDS (16 KB), wave-uniform ds_read_b128 broadcast. 8-wave LDS
// reduction (single pass, 16 vals/thread), then multiplicity-2
// unsafeAtomicAdd into the memset-zeroed output (R1-proven ~free: 1M
// atomics, 2 temporally-staggered addends per line).
__global__ __launch_bounds__(512, 8)
void dereverb_kernel(const float* __restrict__ x,
                     const float* __restrict__ t60s,
                     const float* __restrict__ kw,
                     float* __restrict__ out)
{
    __shared__ float wlds[256 * KSZ];   // 16 KB weight stage (persistent)
    __shared__ float red[4 * RST];      // 17 KB reduction regions

    const int b    = blockIdx.y;
    const int q0   = blockIdx.x * QPB;
    const int cih  = blockIdx.z;        // 0..1: ci half
    const int tid  = threadIdx.x;
    const int lane = tid & 63;
    const int wave = tid >> 6;          // 0..7

    // Per-sample kernel index (uniform): jnp.round = RNE = rintf.
    float t60 = t60s[b & 7];
    int kidx = (int)rintf(t60 * 100.0f) - 10;
    kidx = __builtin_amdgcn_readfirstlane(kidx);

    // Stage this half's 256x16 weights: 1024 float4 / 512 threads = 2 each.
    const float4* wsrc = (const float4*)(kw + ((size_t)kidx * CIN + cih * 256) * KSZ);
    ((float4*)wlds)[tid]       = wsrc[tid];
    ((float4*)wlds)[tid + 512] = wsrc[tid + 512];
    __syncthreads();

    // Lane's q base; clamps keep all loads inside the current row.
    const int qb  = q0 + 2 * lane;                  // 0..4094 (even)
    const int qbl = qb < 3998 ? qb : 3998;          // 8B-aligned float2 base
    const int qan = (qb + 2) < NQ ? (qb + 2) : NQ;  // halo x[q+2]

    const float* xr = x + ((size_t)b * CIN + cih * 256 + wave * 32) * L_IN;
    const float* xp = xr + qbl;
    const float* xq = xr + qan;
    const float4* wv = (const float4*)(wlds + wave * 32 * KSZ);

    float acc[2][8];
    #pragma unroll
    for (int qi = 0; qi < 2; ++qi)
        #pragma unroll
        for (int r = 0; r < 8; ++r) acc[qi][r] = 0.0f;

#define FMA_BODY(A, AN, W0, W1, W2, W3) do {                        \
        const float xl[2] = {(A).x, (A).y};                         \
        const float xh[2] = {(A).y, (AN)};                          \
        const float wa[8] = {(W0).x,(W0).y,(W0).z,(W0).w,           \
                             (W1).x,(W1).y,(W1).z,(W1).w};          \
        const float wb[8] = {(W2).x,(W2).y,(W2).z,(W2).w,           \
                             (W3).x,(W3).y,(W3).z,(W3).w};          \
        _Pragma("unroll")                                           \
        for (int qi = 0; qi < 2; ++qi)                              \
            _Pragma("unroll")                                       \
            for (int r = 0; r < 8; ++r) {                           \
                acc[qi][r] = fmaf(xh[qi], wa[r], acc[qi][r]);       \
                acc[qi][r] = fmaf(xl[qi], wb[r], acc[qi][r]);       \
            }                                                       \
    } while (0)

    // d=2 software-pipelined loop over the wave's 32 ci rows.
    float2 a0 = *(const float2*)xp;
    float  n0 = *xq;
    float2 a1 = *(const float2*)(xp + L_IN);
    float  n1 = *(xq + L_IN);
    float4 w0 = wv[0], w1 = wv[1], w2 = wv[2], w3 = wv[3];

    #pragma unroll 2
    for (int ci = 0; ci < 30; ++ci) {
        float2 a2 = *(const float2*)(xp + 2 * L_IN);   // global prefetch, d=2
        float  n2 = *(xq + 2 * L_IN);
        float4 u0 = wv[4], u1 = wv[5], u2 = wv[6], u3 = wv[7];
        FMA_BODY(a0, n0, w0, w1, w2, w3);
        a0 = a1; n0 = n1; a1 = a2; n1 = n2;
        w0 = u0; w1 = u1; w2 = u2; w3 = u3;
        xp += L_IN; xq += L_IN; wv += 4;
    }
    {   // ci = 30: last weight prefetch; x(31) already in a1/n1
        float4 u0 = wv[4], u1 = wv[5], u2 = wv[6], u3 = wv[7];
        FMA_BODY(a0, n0, w0, w1, w2, w3);
        a0 = a1; n0 = n1;
        w0 = u0; w1 = u1; w2 = u2; w3 = u3;
    }
    FMA_BODY(a0, n0, w0, w1, w2, w3);   // ci = 31

    // Zero contributions from invalid q (> 3998) / clamped lanes.
    #pragma unroll
    for (int qi = 0; qi < 2; ++qi)
        if (qb + qi > NQ - 1)
            #pragma unroll
            for (int r = 0; r < 8; ++r) acc[qi][r] = 0.0f;

    // Single-pass 8-wave reduction: 16 values/thread fit one region write.
    // Region r holds waves {r, r+4}; layout: addr = r*RST + lane*17 + j,
    // j = qi*8 + rr (17-padded chunks, bank-balanced b128 stores).
    if (wave >= 4) {
        float* rp = red + (wave - 4) * RST + lane * 17;
        #pragma unroll
        for (int j = 0; j < 16; ++j)
            rp[j] = acc[j >> 3][j & 7];
    }
    __syncthreads();
    if (wave < 4) {
        float* rp = red + wave * RST + lane * 17;
        #pragma unroll
        for (int j = 0; j < 16; ++j)
            rp[j] += acc[j >> 3][j & 7];
    }
    __syncthreads();

    // Epilogue: 1024 outputs/block, 2 per thread. Thread (l = tid>>4,
    // j = tid&15) covers lanes l and l+32: q_local = 2*l2 + (j>>3),
    // tl = 8*q_local + (j&7). Multiplicity-2 atomic accumulate (cih halves).
    const int j = tid & 15, l = tid >> 4;
    const size_t obase = (size_t)b * LOUT + (size_t)q0 * 8;
    #pragma unroll
    for (int kk = 0; kk < 2; ++kk) {
        const int l2 = l + 32 * kk;
        const int tl = 16 * l2 + 8 * (j >> 3) + (j & 7);
        if (q0 * 8 + tl < LOUT) {       // trims q > 3998 (last tiles only)
            float s = red[0 * RST + l2 * 17 + j]
                    + red[1 * RST + l2 * 17 + j]
                    + red[2 * RST + l2 * 17 + j]
                    + red[3 * RST + l2 * 17 + j];
            unsafeAtomicAdd(out + obase + tl, s);
        }
    }
#undef FMA_BODY
}

extern "C" void kernel_launch(void* const* d_in, const int* in_sizes, int n_in,
                              void* d_out, int out_size, void* d_ws, size_t ws_size,
                              hipStream_t stream) {
    const float* x    = (const float*)d_in[0];   // (16, 512, 4000)
    const float* t60s = (const float*)d_in[1];   // (8,)
    const float* kw   = (const float*)d_in[2];   // (41, 512, 1, 16)
    float* out = (float*)d_out;                  // (16, 1, 31992)

    // Zero-init for the 2-way ci-half atomic accumulation (graph-capturable).
    hipMemsetAsync(d_out, 0, out_size, stream);

    dim3 grid((NQ + QPB - 1) / QPB, 16, 2);      // (32, 16, 2) = 1024 blocks
    dereverb_kernel<<<grid, 512, 0, stream>>>(x, t60s, kw, out);
}